// Round 2
// baseline (237.465 us; speedup 1.0000x reference)
//
#include <hip/hip_runtime.h>
#include <hip/hip_bf16.h>

typedef __bf16 bf16_t;
typedef __bf16 bf16x8 __attribute__((ext_vector_type(8)));
typedef __bf16 bf16x4 __attribute__((ext_vector_type(4)));
typedef float  f32x4  __attribute__((ext_vector_type(4)));

#define D  128
#define BM 128

// LDS element-index swizzle: spreads stride-128 (256B) rows across banks.
// Preserves contiguity of 4-aligned-4 and 8-aligned-8 element groups.
__device__ __forceinline__ int swz(int r, int c) {
    return (r * D + c) ^ ((r & 7) << 3);
}

// Transpose + convert weights to bf16: w1t[n][k] (n<128,k<384), w2t[n][k] (128x128)
__global__ void prep_weights_kernel(const float* __restrict__ W1,
                                    const float* __restrict__ W2,
                                    bf16_t* __restrict__ w1t,
                                    bf16_t* __restrict__ w2t) {
    int tid = blockIdx.x * 256 + threadIdx.x;
    if (tid < 128 * 384) {
        int n = tid / 384, k = tid % 384;
        w1t[tid] = (bf16_t)W1[k * 128 + n];
    } else {
        int t2 = tid - 128 * 384;
        if (t2 < 128 * 128) {
            int n = t2 / 128, k = t2 % 128;
            w2t[t2] = (bf16_t)W2[k * 128 + n];
        }
    }
}

__global__ __launch_bounds__(256, 2)
void fused_edge_mlp_kernel(const float* __restrict__ x,
                           const float* __restrict__ ea,
                           const int* __restrict__ ei,   // int32 on device (harness converts int64)
                           const bf16_t* __restrict__ w1t,
                           const bf16_t* __restrict__ w2t,
                           const float* __restrict__ b1,
                           const float* __restrict__ b2,
                           float* __restrict__ out,
                           long long E) {
    __shared__ __align__(16) bf16_t Ab[BM * D];   // input tile / h tile
    __shared__ __align__(16) bf16_t Bb[D * D];    // weight tile

    const int tid  = threadIdx.x;
    const int lane = tid & 63;
    const int wv   = tid >> 6;      // wave 0..3, owns rows [wv*32, wv*32+32)
    const int col0 = lane & 15;
    const int krow = lane >> 4;     // 0..3
    const long long e0 = (long long)blockIdx.x * BM;

    // staging assignment: 2 threads per row
    const int sr = tid >> 1;            // row 0..127
    const int sh = (tid & 1) * 64;      // element half-offset

    const long long erow = (e0 + sr < E) ? (e0 + sr) : (E - 1);
    const long long src = (long long)ei[erow];
    const long long dst = (long long)ei[E + erow];

    float bias1[8], bias2[8];
#pragma unroll
    for (int n = 0; n < 8; n++) { bias1[n] = b1[n*16 + col0]; bias2[n] = b2[n*16 + col0]; }

    f32x4 acc[2][8];
#pragma unroll
    for (int m = 0; m < 2; m++)
#pragma unroll
        for (int n = 0; n < 8; n++) acc[m][n] = (f32x4){0.f, 0.f, 0.f, 0.f};

    // ---- GEMM1 over 3 K-phases: x[src], x[dst], edge_attr ----
    for (int p = 0; p < 3; p++) {
        const float* rowp = (p == 0) ? (x + src * D)
                          : (p == 1) ? (x + dst * D)
                                     : (ea + erow * D);
        __syncthreads();   // previous phase's MFMA reads done before overwrite
        // stage A: 64 f32 -> bf16 per thread
#pragma unroll
        for (int j = 0; j < 16; j++) {
            f32x4 v = *(const f32x4*)(rowp + sh + j*4);
            bf16x4 hv = { (bf16_t)v.x, (bf16_t)v.y, (bf16_t)v.z, (bf16_t)v.w };
            *(bf16x4*)&Ab[swz(sr, sh + j*4)] = hv;
        }
        // stage B: W1^T slice for this phase
        {
            const bf16_t* wrow = w1t + (long long)sr * 384 + p * 128 + sh;
#pragma unroll
            for (int j = 0; j < 8; j++)
                *(bf16x8*)&Bb[swz(sr, sh + j*8)] = *(const bf16x8*)(wrow + j*8);
        }
        __syncthreads();
#pragma unroll
        for (int kk = 0; kk < 4; kk++) {
            bf16x8 a0 = *(const bf16x8*)&Ab[swz(wv*32 +      col0, kk*32 + krow*8)];
            bf16x8 a1 = *(const bf16x8*)&Ab[swz(wv*32 + 16 + col0, kk*32 + krow*8)];
#pragma unroll
            for (int n = 0; n < 8; n++) {
                bf16x8 bfr = *(const bf16x8*)&Bb[swz(n*16 + col0, kk*32 + krow*8)];
                acc[0][n] = __builtin_amdgcn_mfma_f32_16x16x32_bf16(a0, bfr, acc[0][n], 0, 0, 0);
                acc[1][n] = __builtin_amdgcn_mfma_f32_16x16x32_bf16(a1, bfr, acc[1][n], 0, 0, 0);
            }
        }
    }
    __syncthreads();   // all MFMA reads of Ab/Bb done

    // h = relu(acc + b1) -> Ab (bf16), each wave writes its own rows
#pragma unroll
    for (int m = 0; m < 2; m++)
#pragma unroll
        for (int n = 0; n < 8; n++)
#pragma unroll
            for (int ri = 0; ri < 4; ri++) {
                float hval = fmaxf(acc[m][n][ri] + bias1[n], 0.f);
                int r = wv*32 + m*16 + krow*4 + ri;
                Ab[swz(r, n*16 + col0)] = (bf16_t)hval;
            }
    // stage W2^T
    {
        const bf16_t* wrow = w2t + (long long)sr * 128 + sh;
#pragma unroll
        for (int j = 0; j < 8; j++)
            *(bf16x8*)&Bb[swz(sr, sh + j*8)] = *(const bf16x8*)(wrow + j*8);
    }
#pragma unroll
    for (int m = 0; m < 2; m++)
#pragma unroll
        for (int n = 0; n < 8; n++) acc[m][n] = (f32x4){0.f, 0.f, 0.f, 0.f};
    __syncthreads();

    // ---- GEMM2: out = relu(h @ W2 + b2) ----
#pragma unroll
    for (int kk = 0; kk < 4; kk++) {
        bf16x8 a0 = *(const bf16x8*)&Ab[swz(wv*32 +      col0, kk*32 + krow*8)];
        bf16x8 a1 = *(const bf16x8*)&Ab[swz(wv*32 + 16 + col0, kk*32 + krow*8)];
#pragma unroll
        for (int n = 0; n < 8; n++) {
            bf16x8 bfr = *(const bf16x8*)&Bb[swz(n*16 + col0, kk*32 + krow*8)];
            acc[0][n] = __builtin_amdgcn_mfma_f32_16x16x32_bf16(a0, bfr, acc[0][n], 0, 0, 0);
            acc[1][n] = __builtin_amdgcn_mfma_f32_16x16x32_bf16(a1, bfr, acc[1][n], 0, 0, 0);
        }
    }

    // epilogue: bias2 + relu, f32 store
#pragma unroll
    for (int m = 0; m < 2; m++)
#pragma unroll
        for (int n = 0; n < 8; n++)
#pragma unroll
            for (int ri = 0; ri < 4; ri++) {
                int r = wv*32 + m*16 + krow*4 + ri;
                long long er = e0 + r;
                if (er < E) {
                    float o = fmaxf(acc[m][n][ri] + bias2[n], 0.f);
                    out[er * D + n*16 + col0] = o;
                }
            }
}

extern "C" void kernel_launch(void* const* d_in, const int* in_sizes, int n_in,
                              void* d_out, int out_size, void* d_ws, size_t ws_size,
                              hipStream_t stream) {
    const float* x  = (const float*)d_in[0];
    const float* ea = (const float*)d_in[1];
    const int*   ei = (const int*)d_in[2];
    const float* W1 = (const float*)d_in[3];
    const float* b1 = (const float*)d_in[4];
    const float* W2 = (const float*)d_in[5];
    const float* b2 = (const float*)d_in[6];
    float* out = (float*)d_out;

    const long long E = (long long)in_sizes[1] / D;

    bf16_t* w1t = (bf16_t*)d_ws;            // [128][384] bf16 = 96 KB
    bf16_t* w2t = w1t + 128 * 384;          // [128][128] bf16 = 32 KB

    prep_weights_kernel<<<(128*384 + 128*128 + 255) / 256, 256, 0, stream>>>(W1, W2, w1t, w2t);

    int nblocks = (int)((E + BM - 1) / BM);  // 3125 for E=400000
    fused_edge_mlp_kernel<<<nblocks, 256, 0, stream>>>(x, ea, ei, w1t, w2t, b1, b2, out, E);
}

// Round 3
// 227.655 us; speedup vs baseline: 1.0431x; 1.0431x over previous
//
#include <hip/hip_runtime.h>
#include <hip/hip_bf16.h>

typedef __bf16 bf16_t;
typedef __bf16 bf16x8 __attribute__((ext_vector_type(8)));
typedef float  f32x4  __attribute__((ext_vector_type(4)));

#define D  128
#define BM 64

// LDS element-index swizzle: spreads stride-128-element (256B) rows across banks.
// XOR value is a multiple of 8 elements, so 8-element (16B) aligned groups stay contiguous.
__device__ __forceinline__ int swz(int r, int c) {
    return (r * D + c) ^ ((r & 7) << 3);
}

// Transpose + convert weights to bf16: w1t[n][k] (n<128,k<384), w2t[n][k] (128x128)
__global__ void prep_weights_kernel(const float* __restrict__ W1,
                                    const float* __restrict__ W2,
                                    bf16_t* __restrict__ w1t,
                                    bf16_t* __restrict__ w2t) {
    int tid = blockIdx.x * 256 + threadIdx.x;
    if (tid < 128 * 384) {
        int n = tid / 384, k = tid % 384;
        w1t[tid] = (bf16_t)W1[k * 128 + n];
    } else {
        int t2 = tid - 128 * 384;
        if (t2 < 128 * 128) {
            int n = t2 / 128, k = t2 % 128;
            w2t[t2] = (bf16_t)W2[k * 128 + n];
        }
    }
}

__global__ __launch_bounds__(256, 3)
void fused_edge_mlp_kernel(const float* __restrict__ x,
                           const float* __restrict__ ea,
                           const int* __restrict__ ei,   // int32 on device
                           const bf16_t* __restrict__ w1t,
                           const bf16_t* __restrict__ w2t,
                           const float* __restrict__ b1,
                           const float* __restrict__ b2,
                           float* __restrict__ out,
                           int E) {
    __shared__ __align__(16) bf16_t Bb[D * D];    // 32 KB current weight slice
    __shared__ __align__(16) bf16_t Hb[BM * D];   // 16 KB hidden tile

    const int tid  = threadIdx.x;
    const int lane = tid & 63;
    const int wv   = tid >> 6;        // wave 0..3 owns rows [wv*16, wv*16+16)
    const int col0 = lane & 15;
    const int krow = lane >> 4;       // 0..3
    const int e0   = blockIdx.x * BM;

    const int rA = wv * 16 + col0;                // A-fragment row this lane owns
    const int er = min(e0 + rA, E - 1);
    const int src = ei[er];                       // issue index loads first
    const int dst = ei[E + er];

    // B staging: 2 threads per weight row, 64 elements each
    const int sr = tid >> 1;
    const int sh = (tid & 1) * 64;

    bf16x8 b_next[8];
    f32x4  a_next[8];

    // ---- prologue: issue W1 slice 0 + x[src] gather ----
    {
        const bf16_t* wrow = w1t + sr * 384 + sh;
#pragma unroll
        for (int j = 0; j < 8; j++) b_next[j] = *(const bf16x8*)(wrow + j * 8);
    }
    {
        const float* arow = x + src * D;
#pragma unroll
        for (int kk = 0; kk < 4; kk++) {
            a_next[kk*2]   = *(const f32x4*)(arow + kk*32 + krow*8);
            a_next[kk*2+1] = *(const f32x4*)(arow + kk*32 + krow*8 + 4);
        }
    }

#pragma unroll
    for (int j = 0; j < 8; j++) *(bf16x8*)&Bb[swz(sr, sh + j*8)] = b_next[j];

    bf16x8 a_cur[4];
#pragma unroll
    for (int kk = 0; kk < 4; kk++) {
        f32x4 lo = a_next[kk*2], hi = a_next[kk*2+1];
        a_cur[kk] = (bf16x8){ (bf16_t)lo.x,(bf16_t)lo.y,(bf16_t)lo.z,(bf16_t)lo.w,
                              (bf16_t)hi.x,(bf16_t)hi.y,(bf16_t)hi.z,(bf16_t)hi.w };
    }

    f32x4 acc[8];
#pragma unroll
    for (int n = 0; n < 8; n++) acc[n] = (f32x4){0.f,0.f,0.f,0.f};

    float bias1[8], bias2[8];

    __syncthreads();

    // ---- phases: 0=x[src]·W1a  1=x[dst]·W1b  2=ea·W1c  3=h·W2 ----
#pragma unroll
    for (int p = 0; p < 4; p++) {
        // issue next phase's staging loads (hide under this phase's MFMA)
        if (p < 3) {
            const bf16_t* wrow = (p < 2) ? (w1t + sr * 384 + (p + 1) * 128 + sh)
                                         : (w2t + sr * 128 + sh);
#pragma unroll
            for (int j = 0; j < 8; j++) b_next[j] = *(const bf16x8*)(wrow + j * 8);
        }
        if (p < 2) {
            const float* arow = (p == 0) ? (x + dst * D) : (ea + er * D);
#pragma unroll
            for (int kk = 0; kk < 4; kk++) {
                a_next[kk*2]   = *(const f32x4*)(arow + kk*32 + krow*8);
                a_next[kk*2+1] = *(const f32x4*)(arow + kk*32 + krow*8 + 4);
            }
        }
        if (p == 1) {
#pragma unroll
            for (int n = 0; n < 8; n++) bias1[n] = b1[n*16 + col0];
        }
        if (p == 2) {
#pragma unroll
            for (int n = 0; n < 8; n++) bias2[n] = b2[n*16 + col0];
        }

        // MFMA for this phase
#pragma unroll
        for (int kk = 0; kk < 4; kk++) {
            bf16x8 a;
            if (p < 3) a = a_cur[kk];
            else       a = *(const bf16x8*)&Hb[swz(wv*16 + col0, kk*32 + krow*8)];
#pragma unroll
            for (int n = 0; n < 8; n++) {
                bf16x8 b = *(const bf16x8*)&Bb[swz(n*16 + col0, kk*32 + krow*8)];
                acc[n] = __builtin_amdgcn_mfma_f32_16x16x32_bf16(a, b, acc[n], 0, 0, 0);
            }
        }

        if (p < 2) {
            // convert prefetched A rows for the next phase
#pragma unroll
            for (int kk = 0; kk < 4; kk++) {
                f32x4 lo = a_next[kk*2], hi = a_next[kk*2+1];
                a_cur[kk] = (bf16x8){ (bf16_t)lo.x,(bf16_t)lo.y,(bf16_t)lo.z,(bf16_t)lo.w,
                                      (bf16_t)hi.x,(bf16_t)hi.y,(bf16_t)hi.z,(bf16_t)hi.w };
            }
        }
        if (p == 2) {
            // h = relu(acc + b1) -> Hb (bf16), reset acc for GEMM2
#pragma unroll
            for (int n = 0; n < 8; n++)
#pragma unroll
                for (int ri = 0; ri < 4; ri++) {
                    float hv = fmaxf(acc[n][ri] + bias1[n], 0.f);
                    Hb[swz(wv*16 + krow*4 + ri, n*16 + col0)] = (bf16_t)hv;
                }
#pragma unroll
            for (int n = 0; n < 8; n++) acc[n] = (f32x4){0.f,0.f,0.f,0.f};
        }
        if (p < 3) {
            __syncthreads();                       // all waves done reading Bb (and Hb writes done at p==2)
#pragma unroll
            for (int j = 0; j < 8; j++) *(bf16x8*)&Bb[swz(sr, sh + j*8)] = b_next[j];
            __syncthreads();
        }
    }

    // ---- epilogue: out = relu(acc + b2) ----
#pragma unroll
    for (int n = 0; n < 8; n++)
#pragma unroll
        for (int ri = 0; ri < 4; ri++) {
            int row = wv*16 + krow*4 + ri;
            int e = e0 + row;
            if (e < E) out[e * D + n*16 + col0] = fmaxf(acc[n][ri] + bias2[n], 0.f);
        }
}

extern "C" void kernel_launch(void* const* d_in, const int* in_sizes, int n_in,
                              void* d_out, int out_size, void* d_ws, size_t ws_size,
                              hipStream_t stream) {
    const float* x  = (const float*)d_in[0];
    const float* ea = (const float*)d_in[1];
    const int*   ei = (const int*)d_in[2];
    const float* W1 = (const float*)d_in[3];
    const float* b1 = (const float*)d_in[4];
    const float* W2 = (const float*)d_in[5];
    const float* b2 = (const float*)d_in[6];
    float* out = (float*)d_out;

    const int E = in_sizes[1] / D;

    bf16_t* w1t = (bf16_t*)d_ws;            // [128][384] bf16 = 96 KB
    bf16_t* w2t = w1t + 128 * 384;          // [128][128] bf16 = 32 KB

    prep_weights_kernel<<<(128*384 + 128*128 + 255) / 256, 256, 0, stream>>>(W1, W2, w1t, w2t);

    int nblocks = (E + BM - 1) / BM;        // 6250 for E=400000
    fused_edge_mlp_kernel<<<nblocks, 256, 0, stream>>>(x, ea, ei, w1t, w2t, b1, b2, out, E);
}

// Round 4
// 144.207 us; speedup vs baseline: 1.6467x; 1.5787x over previous
//
#include <hip/hip_runtime.h>
#include <hip/hip_bf16.h>

typedef __bf16 bf16_t;
typedef __bf16 bf16x8 __attribute__((ext_vector_type(8)));
typedef __bf16 bf16x4 __attribute__((ext_vector_type(4)));
typedef float  f32x4  __attribute__((ext_vector_type(4)));

#define D  128
#define BM 128

// LDS element-index swizzle: XOR multiples of 8 elems (16B) keep 4/8-elem groups intact.
__device__ __forceinline__ int swz(int r, int c) {
    return (r * D + c) ^ ((r & 7) << 3);
}

// Weights as 4 slice-major tiles [s][n][k], bf16, transposed:
//  s<3:  ws[s*16384 + n*128 + k] = W1[(s*128+k)*128 + n]
//  s==3: ws[3*16384 + n*128 + k] = W2[k*128 + n]
__global__ void prep_weights_kernel(const float* __restrict__ W1,
                                    const float* __restrict__ W2,
                                    bf16_t* __restrict__ ws) {
    int t = blockIdx.x * 256 + threadIdx.x;       // 65536 total
    int s = t >> 14, r = t & 16383;
    int n = r >> 7, k = r & 127;
    float v = (s < 3) ? W1[(s * 128 + k) * 128 + n] : W2[k * 128 + n];
    ws[t] = (bf16_t)v;
}

__global__ __launch_bounds__(256, 2)
void fused_edge_mlp_kernel(const float* __restrict__ x,
                           const float* __restrict__ ea,
                           const int* __restrict__ ei,
                           const bf16_t* __restrict__ ws,
                           const float* __restrict__ b1,
                           const float* __restrict__ b2,
                           float* __restrict__ out,
                           int E) {
    __shared__ __align__(16) bf16_t Ab[BM * D];   // 32 KB: A tile / H tile (wave-private chunks)
    __shared__ __align__(16) bf16_t Bb[D * D];    // 32 KB: current weight slice

    const int tid  = threadIdx.x;
    const int lane = tid & 63;
    const int wv   = tid >> 6;        // wave 0..3, owns rows [wv*32, wv*32+32)
    const int col0 = lane & 15;
    const int krow = lane >> 4;       // 0..3
    const int l31  = lane & 31;
    const int half = lane >> 5;       // 0/1
    const int e0   = blockIdx.x * BM;

    // per-lane edge indices for this wave's 32 rows (lanes 32..63 duplicate 0..31)
    const int erL  = min(e0 + wv * 32 + l31, E - 1);
    const int sidx = ei[erL];
    const int didx = ei[E + erL];

    // B staging: instr j covers rows [j*16, j*16+16), 16B slot per thread (1KB/wave contiguous)
    const int brow_t = tid >> 4;          // 0..15
    const int bslot  = (tid & 15) * 8;    // element offset

    f32x4  abuf[16];
    bf16x8 bnext[8];

    // ---- prologue: B slice 0 + A0 = x[src] rows (coalesced: 32 lanes span one 512B row) ----
    {
        const bf16_t* base = ws;          // slice 0
#pragma unroll
        for (int j = 0; j < 8; j++)
            bnext[j] = *(const bf16x8*)(base + (j * 16 + brow_t) * 128 + bslot);
    }
#pragma unroll
    for (int j = 0; j < 16; j++) {
        int r = j * 2 + half;                       // local row 0..31
        int g = __shfl(sidx, r);
        abuf[j] = *(const f32x4*)(x + (long long)g * D + l31 * 4);
    }

    float bias1[8], bias2[8];
#pragma unroll
    for (int n = 0; n < 8; n++) { bias1[n] = b1[n*16 + col0]; bias2[n] = b2[n*16 + col0]; }

    // write B0 (all threads, disjoint), write A0 (wave-private), then one barrier
#pragma unroll
    for (int j = 0; j < 8; j++)
        *(bf16x8*)&Bb[swz(j * 16 + brow_t, bslot)] = bnext[j];
#pragma unroll
    for (int j = 0; j < 16; j++) {
        int r = j * 2 + half;
        f32x4 v = abuf[j];
        bf16x4 hv = { (bf16_t)v.x, (bf16_t)v.y, (bf16_t)v.z, (bf16_t)v.w };
        *(bf16x4*)&Ab[swz(wv * 32 + r, l31 * 4)] = hv;
    }
    __syncthreads();

    f32x4 acc[2][8];
#pragma unroll
    for (int m = 0; m < 2; m++)
#pragma unroll
        for (int n = 0; n < 8; n++) acc[m][n] = (f32x4){0.f, 0.f, 0.f, 0.f};

    // ---- phases: 0=x[src]·W1a  1=x[dst]·W1b  2=ea·W1c  3=h·W2 ----
#pragma unroll
    for (int p = 0; p < 4; p++) {
        // prefetch next weight slice (1KB-contiguous per wave-instr, L2-hot)
        if (p < 3) {
            const bf16_t* base = ws + (p + 1) * 16384;
#pragma unroll
            for (int j = 0; j < 8; j++)
                bnext[j] = *(const bf16x8*)(base + (j * 16 + brow_t) * 128 + bslot);
        }
        // prefetch next A rows (p0: x[dst] gather 512B bursts; p1: ea 1KB streams)
        if (p < 2) {
#pragma unroll
            for (int j = 0; j < 16; j++) {
                int r = j * 2 + half;
                const float* rp;
                if (p == 0) { int g = __shfl(didx, r); rp = x + (long long)g * D; }
                else        { int e = min(e0 + wv * 32 + r, E - 1); rp = ea + (long long)e * D; }
                abuf[j] = *(const f32x4*)(rp + l31 * 4);
            }
        }

        // MFMA for this phase (A/H fragments from this wave's private chunk)
#pragma unroll
        for (int kk = 0; kk < 4; kk++) {
            bf16x8 a0 = *(const bf16x8*)&Ab[swz(wv*32 +      col0, kk*32 + krow*8)];
            bf16x8 a1 = *(const bf16x8*)&Ab[swz(wv*32 + 16 + col0, kk*32 + krow*8)];
#pragma unroll
            for (int n = 0; n < 8; n++) {
                bf16x8 b = *(const bf16x8*)&Bb[swz(n*16 + col0, kk*32 + krow*8)];
                acc[0][n] = __builtin_amdgcn_mfma_f32_16x16x32_bf16(a0, b, acc[0][n], 0, 0, 0);
                acc[1][n] = __builtin_amdgcn_mfma_f32_16x16x32_bf16(a1, b, acc[1][n], 0, 0, 0);
            }
        }

        // write next A into my chunk (wave-private; LDS pipe is in-order per wave)
        if (p < 2) {
#pragma unroll
            for (int j = 0; j < 16; j++) {
                int r = j * 2 + half;
                f32x4 v = abuf[j];
                bf16x4 hv = { (bf16_t)v.x, (bf16_t)v.y, (bf16_t)v.z, (bf16_t)v.w };
                *(bf16x4*)&Ab[swz(wv * 32 + r, l31 * 4)] = hv;
            }
        }
        // h = relu(acc + b1) -> my chunk (becomes GEMM2's A), reset acc
        if (p == 2) {
#pragma unroll
            for (int m = 0; m < 2; m++)
#pragma unroll
                for (int n = 0; n < 8; n++)
#pragma unroll
                    for (int ri = 0; ri < 4; ri++) {
                        float hv = fmaxf(acc[m][n][ri] + bias1[n], 0.f);
                        Ab[swz(wv*32 + m*16 + krow*4 + ri, n*16 + col0)] = (bf16_t)hv;
                    }
#pragma unroll
            for (int m = 0; m < 2; m++)
#pragma unroll
                for (int n = 0; n < 8; n++) acc[m][n] = (f32x4){0.f, 0.f, 0.f, 0.f};
        }
        // rotate weight slice (only block-wide sync points)
        if (p < 3) {
            __syncthreads();
#pragma unroll
            for (int j = 0; j < 8; j++)
                *(bf16x8*)&Bb[swz(j * 16 + brow_t, bslot)] = bnext[j];
            __syncthreads();
        }
    }

    // ---- epilogue: out = relu(acc + b2) ----
#pragma unroll
    for (int m = 0; m < 2; m++)
#pragma unroll
        for (int n = 0; n < 8; n++)
#pragma unroll
            for (int ri = 0; ri < 4; ri++) {
                int row = wv*32 + m*16 + krow*4 + ri;
                int e = e0 + row;
                if (e < E) out[(long long)e * D + n*16 + col0] = fmaxf(acc[m][n][ri] + bias2[n], 0.f);
            }
}

extern "C" void kernel_launch(void* const* d_in, const int* in_sizes, int n_in,
                              void* d_out, int out_size, void* d_ws, size_t ws_size,
                              hipStream_t stream) {
    const float* x  = (const float*)d_in[0];
    const float* ea = (const float*)d_in[1];
    const int*   ei = (const int*)d_in[2];
    const float* W1 = (const float*)d_in[3];
    const float* b1 = (const float*)d_in[4];
    const float* W2 = (const float*)d_in[5];
    const float* b2 = (const float*)d_in[6];
    float* out = (float*)d_out;

    const int E = in_sizes[1] / D;

    bf16_t* wsl = (bf16_t*)d_ws;    // 4 slices x 128x128 bf16 = 128 KB

    prep_weights_kernel<<<256, 256, 0, stream>>>(W1, W2, wsl);

    int nblocks = (E + BM - 1) / BM;    // 3125 for E=400000
    fused_edge_mlp_kernel<<<nblocks, 256, 0, stream>>>(x, ea, ei, wsl, b1, b2, out, E);
}